// Round 1
// baseline (236.005 us; speedup 1.0000x reference)
//
#include <hip/hip_runtime.h>
#include <hip/hip_bf16.h>

#define NN 50000
#define EE 800000
#define CC 64
#define HH 2
#define LL 3
#define CAP 64     // slots per node (Poisson(16): P(>=64) ~ 1e-13)
#define NB 782     // dst buckets of 64 nodes: (50000+63)/64
#define BCAP 1280  // per-bucket capacity (mean 1023, +8 sigma)
#define CHUNK 8192 // edges per k_bin block
#define NBLK ((EE + CHUNK - 1) / CHUNK)   // 98

// ---------------- build ----------------

// Block-local counting sort (R11 structure, 1024 threads for latency hiding):
// LDS stash + LDS histogram, ONE global atomic per (block,bucket) (77k vs
// 800k — device atomics serialize at the fabric), then place at base+rank.
__global__ __launch_bounds__(1024) void k_bin(const int* __restrict__ ei,
                                              int* __restrict__ bcnt,
                                              unsigned int* __restrict__ bucket) {
    __shared__ unsigned int stash[CHUNK];
    __shared__ int hist[NB];
    __shared__ int rank[NB];
    __shared__ int base[NB];

    int c0 = blockIdx.x * CHUNK;
    int n = EE - c0; if (n > CHUNK) n = CHUNK;

    for (int b = threadIdx.x; b < NB; b += 1024) { hist[b] = 0; rank[b] = 0; }
    __syncthreads();

    for (int k = threadIdx.x; k < n; k += 1024) {
        unsigned int s = (unsigned int)ei[c0 + k];
        unsigned int d = (unsigned int)ei[EE + c0 + k];
        stash[k] = (d << 16) | s;
        atomicAdd(&hist[d >> 6], 1);
    }
    __syncthreads();

    for (int b = threadIdx.x; b < NB; b += 1024) {
        int c = hist[b];
        base[b] = c ? atomicAdd(&bcnt[b], c) : 0;
    }
    __syncthreads();

    for (int k = threadIdx.x; k < n; k += 1024) {
        unsigned int pk = stash[k];
        int b = (int)(pk >> 22);
        int r = atomicAdd(&rank[b], 1);
        int pos = base[b] + r;
        if (pos < BCAP) bucket[(size_t)b * BCAP + pos] = pk;
    }
}

// one block per bucket; bucket b exclusively owns dsts [64b,64b+64) -> LDS
// rank counters (no global atomics); cnt written coalesced.
__global__ __launch_bounds__(256) void k_place(const unsigned int* __restrict__ bucket,
                                               const int* __restrict__ bcnt,
                                               int* __restrict__ cnt,
                                               unsigned short* __restrict__ slots) {
    __shared__ int lcnt[64];
    int b = blockIdx.x;
    if (threadIdx.x < 64) lcnt[threadIdx.x] = 0;
    __syncthreads();
    int node0 = b << 6;
    int m = bcnt[b];
    if (m > BCAP) m = BCAP;
    const unsigned int* src = bucket + (size_t)b * BCAP;
    for (int i = threadIdx.x; i < m; i += 256) {
        unsigned int pk = src[i];
        int d = (int)(pk >> 16);
        int s = (int)(pk & 0xFFFFu);
        int pos = atomicAdd(&lcnt[d - node0], 1);
        if (pos < CAP) slots[(size_t)d * CAP + pos] = (unsigned short)s;
    }
    __syncthreads();
    if (threadIdx.x < 64) {
        int node = node0 + threadIdx.x;
        if (node < NN) cnt[node] = lcnt[threadIdx.x];
    }
}

// ---------------- fused GAT layer ----------------
// R12: wave per node; 8 subgroups x 8 lanes; lane holds 8 channels (2 quads).
// vs R11 (16-lane subgroups): per-edge reduce 4->3 levels, exp/index/loop
// overhead halves (16 edges/wave-iter), and ALL reduce shuffles move from
// ds_swizzle (LDS pipe, lgkmcnt stalls) to DPP adds (VALU, fused add_dpp).
// ~13.6 -> ~9.4 wave-instr/edge. Epilogue uses linear-merge: merge s only,
// normalize per-subgroup partials, merge the 8 output channels (not 18 accs).

#define LEAKY(v) fmaxf((v), 0.2f * (v))

template <int CTRL>
__device__ __forceinline__ float dpp_add(float v) {
    int t = __builtin_amdgcn_update_dpp(0, __float_as_int(v), CTRL, 0xF, 0xF, true);
    return v + __int_as_float(t);
}

// sum over the 8 lanes of a subgroup (subgroups are 8-lane aligned)
__device__ __forceinline__ float red8(float v) {
    v = dpp_add<0xB1>(v);    // quad_perm [1,0,3,2]  = lane^1
    v = dpp_add<0x4E>(v);    // quad_perm [2,3,0,1]  = lane^2
    v = dpp_add<0x141>(v);   // row_half_mirror      = lane^7 (quads uniform)
    return v;
}

// sum across the 8 subgroups (values may differ per lane within a subgroup)
__device__ __forceinline__ float merge8(float v) {
    v = dpp_add<0x128>(v);   // row_ror:8 = lane^8 within each 16-lane row
    v += __shfl_xor(v, 16);
    v += __shfl_xor(v, 32);
    return v;
}

__device__ __forceinline__ float4 addleaky(float4 v, float4 d) {
    float4 r;
    r.x = LEAKY(v.x + d.x); r.y = LEAKY(v.y + d.y);
    r.z = LEAKY(v.z + d.z); r.w = LEAKY(v.w + d.w);
    return r;
}

__device__ __forceinline__ float dot8(float4 al, float4 ah, float4 vl, float4 vh) {
    // two independent 4-FMA chains + one add (ILP)
    float lo = fmaf(vl.w, al.w, fmaf(vl.z, al.z, fmaf(vl.y, al.y, vl.x * al.x)));
    float hi = fmaf(vh.w, ah.w, fmaf(vh.z, ah.z, fmaf(vh.y, ah.y, vh.x * ah.x)));
    return lo + hi;
}

template <bool FIRST>
__global__ __launch_bounds__(256) void k_gat(const float* __restrict__ h,
                                             const int* __restrict__ cnt,
                                             const unsigned short* __restrict__ slots,
                                             const float* __restrict__ att_l,
                                             const float* __restrict__ bias_l,
                                             float* __restrict__ h_out,
                                             float* __restrict__ acc, int n) {
    int wid = threadIdx.x >> 6;
    int lane = threadIdx.x & 63;
    int node = blockIdx.x * 4 + wid;
    if (node >= n) return;
    int sub = lane >> 3, t = lane & 7;
    unsigned tb = (unsigned)t << 5;                 // byte offset of lane's 32B
    const char* hl = (const char*)h + tb;
    const float4* attq = (const float4*)att_l;
    float4 a0l = attq[2 * t],      a0h = attq[2 * t + 1];
    float4 a1l = attq[16 + 2 * t], a1h = attq[16 + 2 * t + 1];
    float4 hdl = *(const float4*)(hl + ((unsigned)node << 8));
    float4 hdh = *(const float4*)(hl + ((unsigned)node << 8) + 16);
    int deg = cnt[node];
    if (deg > CAP) deg = CAP;
    const unsigned* rowu = (const unsigned*)(slots + (size_t)node * CAP);

    float s0, s1;
    float4 A0l, A0h, A1l, A1h;

    // self-loop: all 8 subgroups, weight 1/8 (merge restores 1x) — no branch
    {
        float4 u = addleaky(hdl, hdl);              // leaky(2*hd) low quad
        float4 v = addleaky(hdh, hdh);
        float p0 = red8(dot8(a0l, a0h, u, v));
        float p1 = red8(dot8(a1l, a1h, u, v));
        float e0 = 0.125f * __expf(p0), e1 = 0.125f * __expf(p1);
        s0 = e0; s1 = e1;
        A0l.x = e0 * hdl.x; A0l.y = e0 * hdl.y; A0l.z = e0 * hdl.z; A0l.w = e0 * hdl.w;
        A0h.x = e0 * hdh.x; A0h.y = e0 * hdh.y; A0h.z = e0 * hdh.z; A0h.w = e0 * hdh.w;
        A1l.x = e1 * hdl.x; A1l.y = e1 * hdl.y; A1l.z = e1 * hdl.z; A1l.w = e1 * hdl.w;
        A1h.x = e1 * hdh.x; A1h.y = e1 * hdh.y; A1h.z = e1 * hdh.z; A1h.w = e1 * hdh.w;
    }

    // main loop: subgroup takes edge pairs (2p, 2p+1) — one u32 = both indices
    int npair = deg >> 1;
    for (int p = sub; p < npair; p += 8) {
        unsigned pk = rowu[p];
        unsigned oa = (pk & 0xFFFFu) << 8;
        unsigned ob = (pk & 0xFFFF0000u) >> 8;       // (pk>>16)<<8
        float4 va_l = *(const float4*)(hl + oa);
        float4 va_h = *(const float4*)(hl + oa + 16);
        float4 vb_l = *(const float4*)(hl + ob);
        float4 vb_h = *(const float4*)(hl + ob + 16);
        float4 la_l = addleaky(va_l, hdl), la_h = addleaky(va_h, hdh);
        float4 lb_l = addleaky(vb_l, hdl), lb_h = addleaky(vb_h, hdh);
        float pa0 = red8(dot8(a0l, a0h, la_l, la_h));
        float pa1 = red8(dot8(a1l, a1h, la_l, la_h));
        float pb0 = red8(dot8(a0l, a0h, lb_l, lb_h));
        float pb1 = red8(dot8(a1l, a1h, lb_l, lb_h));
        float ea0 = __expf(pa0), ea1 = __expf(pa1);
        float eb0 = __expf(pb0), eb1 = __expf(pb1);
        s0 += ea0 + eb0;
        s1 += ea1 + eb1;
        A0l.x = fmaf(ea0, va_l.x, fmaf(eb0, vb_l.x, A0l.x));
        A0l.y = fmaf(ea0, va_l.y, fmaf(eb0, vb_l.y, A0l.y));
        A0l.z = fmaf(ea0, va_l.z, fmaf(eb0, vb_l.z, A0l.z));
        A0l.w = fmaf(ea0, va_l.w, fmaf(eb0, vb_l.w, A0l.w));
        A0h.x = fmaf(ea0, va_h.x, fmaf(eb0, vb_h.x, A0h.x));
        A0h.y = fmaf(ea0, va_h.y, fmaf(eb0, vb_h.y, A0h.y));
        A0h.z = fmaf(ea0, va_h.z, fmaf(eb0, vb_h.z, A0h.z));
        A0h.w = fmaf(ea0, va_h.w, fmaf(eb0, vb_h.w, A0h.w));
        A1l.x = fmaf(ea1, va_l.x, fmaf(eb1, vb_l.x, A1l.x));
        A1l.y = fmaf(ea1, va_l.y, fmaf(eb1, vb_l.y, A1l.y));
        A1l.z = fmaf(ea1, va_l.z, fmaf(eb1, vb_l.z, A1l.z));
        A1l.w = fmaf(ea1, va_l.w, fmaf(eb1, vb_l.w, A1l.w));
        A1h.x = fmaf(ea1, va_h.x, fmaf(eb1, vb_h.x, A1h.x));
        A1h.y = fmaf(ea1, va_h.y, fmaf(eb1, vb_h.y, A1h.y));
        A1h.z = fmaf(ea1, va_h.z, fmaf(eb1, vb_h.z, A1h.z));
        A1h.w = fmaf(ea1, va_h.w, fmaf(eb1, vb_h.w, A1h.w));
    }

    // tail: one odd edge, handled by one subgroup (uniform per subgroup)
    if (deg & 1) {
        int tl = deg - 1;
        if (sub == (npair & 7)) {
            unsigned s = ((const unsigned short*)rowu)[tl];
            unsigned o = s << 8;
            float4 v_l = *(const float4*)(hl + o);
            float4 v_h = *(const float4*)(hl + o + 16);
            float4 l_l = addleaky(v_l, hdl), l_h = addleaky(v_h, hdh);
            float p0 = red8(dot8(a0l, a0h, l_l, l_h));
            float p1 = red8(dot8(a1l, a1h, l_l, l_h));
            float e0 = __expf(p0), e1 = __expf(p1);
            s0 += e0; s1 += e1;
            A0l.x = fmaf(e0, v_l.x, A0l.x); A0l.y = fmaf(e0, v_l.y, A0l.y);
            A0l.z = fmaf(e0, v_l.z, A0l.z); A0l.w = fmaf(e0, v_l.w, A0l.w);
            A0h.x = fmaf(e0, v_h.x, A0h.x); A0h.y = fmaf(e0, v_h.y, A0h.y);
            A0h.z = fmaf(e0, v_h.z, A0h.z); A0h.w = fmaf(e0, v_h.w, A0h.w);
            A1l.x = fmaf(e1, v_l.x, A1l.x); A1l.y = fmaf(e1, v_l.y, A1l.y);
            A1l.z = fmaf(e1, v_l.z, A1l.z); A1l.w = fmaf(e1, v_l.w, A1l.w);
            A1h.x = fmaf(e1, v_h.x, A1h.x); A1h.y = fmaf(e1, v_h.y, A1h.y);
            A1h.z = fmaf(e1, v_h.z, A1h.z); A1h.w = fmaf(e1, v_h.w, A1h.w);
        }
    }

    // linear merge: totals of s first (softmax denom), then normalize the
    // per-subgroup partials and merge only the 8 output channels.
    s0 = merge8(s0);
    s1 = merge8(s1);
    float inv0 = 0.5f / (s0 + 1e-16f);               // fold mean-over-heads
    float inv1 = 0.5f / (s1 + 1e-16f);
    float4 o_l, o_h;
    o_l.x = fmaf(A1l.x, inv1, A0l.x * inv0);
    o_l.y = fmaf(A1l.y, inv1, A0l.y * inv0);
    o_l.z = fmaf(A1l.z, inv1, A0l.z * inv0);
    o_l.w = fmaf(A1l.w, inv1, A0l.w * inv0);
    o_h.x = fmaf(A1h.x, inv1, A0h.x * inv0);
    o_h.y = fmaf(A1h.y, inv1, A0h.y * inv0);
    o_h.z = fmaf(A1h.z, inv1, A0h.z * inv0);
    o_h.w = fmaf(A1h.w, inv1, A0h.w * inv0);
    o_l.x = merge8(o_l.x); o_l.y = merge8(o_l.y);
    o_l.z = merge8(o_l.z); o_l.w = merge8(o_l.w);
    o_h.x = merge8(o_h.x); o_h.y = merge8(o_h.y);
    o_h.z = merge8(o_h.z); o_h.w = merge8(o_h.w);

    if (sub == 0) {
        float4 b_l = ((const float4*)bias_l)[2 * t];
        float4 b_h = ((const float4*)bias_l)[2 * t + 1];
        o_l.x += b_l.x; o_l.y += b_l.y; o_l.z += b_l.z; o_l.w += b_l.w;
        o_h.x += b_h.x; o_h.y += b_h.y; o_h.z += b_h.z; o_h.w += b_h.w;
        float4* outp = (float4*)h_out + (size_t)node * 16 + 2 * t;
        outp[0] = o_l; outp[1] = o_h;
        float4* accp = (float4*)acc + (size_t)node * 16 + 2 * t;
        float4 c0, c1;
        if (FIRST) {
            // acc = 0.25*(x + h1); hd holds x's row
            c0.x = 0.25f * (hdl.x + o_l.x); c0.y = 0.25f * (hdl.y + o_l.y);
            c0.z = 0.25f * (hdl.z + o_l.z); c0.w = 0.25f * (hdl.w + o_l.w);
            c1.x = 0.25f * (hdh.x + o_h.x); c1.y = 0.25f * (hdh.y + o_h.y);
            c1.z = 0.25f * (hdh.z + o_h.z); c1.w = 0.25f * (hdh.w + o_h.w);
        } else {
            c0 = accp[0]; c1 = accp[1];
            c0.x += 0.25f * o_l.x; c0.y += 0.25f * o_l.y;
            c0.z += 0.25f * o_l.z; c0.w += 0.25f * o_l.w;
            c1.x += 0.25f * o_h.x; c1.y += 0.25f * o_h.y;
            c1.z += 0.25f * o_h.z; c1.w += 0.25f * o_h.w;
        }
        accp[0] = c0; accp[1] = c1;
    }
}

// ---------------- launch ----------------

static inline size_t align256(size_t x) { return (x + 255) & ~(size_t)255; }

extern "C" void kernel_launch(void* const* d_in, const int* in_sizes, int n_in,
                              void* d_out, int out_size, void* d_ws, size_t ws_size,
                              hipStream_t stream) {
    const float* x    = (const float*)d_in[0];
    const int*   ei   = (const int*)d_in[1];
    const float* att  = (const float*)d_in[2];
    const float* bias = (const float*)d_in[3];
    float* acc = (float*)d_out;   // fp32 output; feats-mean accumulated here

    char* w = (char*)d_ws;
    int* bcnt   = (int*)w;              w += align256((size_t)NB * sizeof(int));
    int* cnt    = (int*)w;              w += align256((size_t)NN * sizeof(int));
    unsigned int* bucket = (unsigned int*)w;
    w += align256((size_t)NB * BCAP * sizeof(unsigned int));
    unsigned short* slots = (unsigned short*)w;
    w += align256((size_t)NN * CAP * sizeof(unsigned short));
    float* hA   = (float*)w;            w += align256((size_t)NN * CC * sizeof(float));
    float* hB   = (float*)w;            w += align256((size_t)NN * CC * sizeof(float));

    const int B = 256;

    // build (per call; ws is re-poisoned before every launch)
    hipMemsetAsync(bcnt, 0, (size_t)NB * sizeof(int), stream);
    k_bin<<<NBLK, 1024, 0, stream>>>(ei, bcnt, bucket);
    k_place<<<NB, B, 0, stream>>>(bucket, bcnt, cnt, slots);

    // 3 fused GAT layers; layer 0 reads x directly and seeds acc = 0.25*(x + h1)
    k_gat<true><<<(NN + 3) / 4, B, 0, stream>>>(
        x, cnt, slots, att, bias, hA, acc, NN);
    k_gat<false><<<(NN + 3) / 4, B, 0, stream>>>(
        hA, cnt, slots, att + (size_t)HH * CC, bias + CC, hB, acc, NN);
    k_gat<false><<<(NN + 3) / 4, B, 0, stream>>>(
        hB, cnt, slots, att + (size_t)2 * HH * CC, bias + 2 * CC, hA, acc, NN);
}

// Round 2
// 200.163 us; speedup vs baseline: 1.1791x; 1.1791x over previous
//
#include <hip/hip_runtime.h>
#include <hip/hip_bf16.h>

#define NN 50000
#define EE 800000
#define CC 64
#define HH 2
#define LL 3
#define CAP 64     // slots per node (Poisson(16): P(>=64) ~ 1e-13)
#define NB 782     // dst buckets of 64 nodes: (50000+63)/64
#define BCAP 1280  // per-bucket capacity (mean 1023, +8 sigma)
#define CHUNK 8192 // edges per k_bin block
#define NBLK ((EE + CHUNK - 1) / CHUNK)   // 98

// ---------------- build ----------------

// Block-local counting sort (R11 structure, 1024 threads for latency hiding):
// LDS stash + LDS histogram, ONE global atomic per (block,bucket) (77k vs
// 800k — device atomics serialize at the fabric), then place at base+rank.
__global__ __launch_bounds__(1024) void k_bin(const int* __restrict__ ei,
                                              int* __restrict__ bcnt,
                                              unsigned int* __restrict__ bucket) {
    __shared__ unsigned int stash[CHUNK];
    __shared__ int hist[NB];
    __shared__ int rank[NB];
    __shared__ int base[NB];

    int c0 = blockIdx.x * CHUNK;
    int n = EE - c0; if (n > CHUNK) n = CHUNK;

    for (int b = threadIdx.x; b < NB; b += 1024) { hist[b] = 0; rank[b] = 0; }
    __syncthreads();

    for (int k = threadIdx.x; k < n; k += 1024) {
        unsigned int s = (unsigned int)ei[c0 + k];
        unsigned int d = (unsigned int)ei[EE + c0 + k];
        stash[k] = (d << 16) | s;
        atomicAdd(&hist[d >> 6], 1);
    }
    __syncthreads();

    for (int b = threadIdx.x; b < NB; b += 1024) {
        int c = hist[b];
        base[b] = c ? atomicAdd(&bcnt[b], c) : 0;
    }
    __syncthreads();

    for (int k = threadIdx.x; k < n; k += 1024) {
        unsigned int pk = stash[k];
        int b = (int)(pk >> 22);
        int r = atomicAdd(&rank[b], 1);
        int pos = base[b] + r;
        if (pos < BCAP) bucket[(size_t)b * BCAP + pos] = pk;
    }
}

// one block per bucket; bucket b exclusively owns dsts [64b,64b+64) -> LDS
// rank counters (no global atomics); cnt written coalesced.
__global__ __launch_bounds__(256) void k_place(const unsigned int* __restrict__ bucket,
                                               const int* __restrict__ bcnt,
                                               int* __restrict__ cnt,
                                               unsigned short* __restrict__ slots) {
    __shared__ int lcnt[64];
    int b = blockIdx.x;
    if (threadIdx.x < 64) lcnt[threadIdx.x] = 0;
    __syncthreads();
    int node0 = b << 6;
    int m = bcnt[b];
    if (m > BCAP) m = BCAP;
    const unsigned int* src = bucket + (size_t)b * BCAP;
    for (int i = threadIdx.x; i < m; i += 256) {
        unsigned int pk = src[i];
        int d = (int)(pk >> 16);
        int s = (int)(pk & 0xFFFFu);
        int pos = atomicAdd(&lcnt[d - node0], 1);
        if (pos < CAP) slots[(size_t)d * CAP + pos] = (unsigned short)s;
    }
    __syncthreads();
    if (threadIdx.x < 64) {
        int node = node0 + threadIdx.x;
        if (node < NN) cnt[node] = lcnt[threadIdx.x];
    }
}

// ---------------- fused GAT layer ----------------
// R13 = R11 structure (wave per node; 4 subgroups x 16 lanes; lane holds one
// channel quad -> ONE contiguous dwordx4 per row per lane: proven coalescing)
// + ONE isolated change: the 4-level per-edge reduce moves from __shfl_xor
// (ds_swizzle on the LDS pipe + dependent v_add, ~4x25cy lgkm chain per iter)
// to fused v_add_f32_dpp (VALU, no lgkm). xor4/xor8 use row_half_mirror /
// row_mirror, valid because values are quad-/half-uniform at those levels.
// R12's 8-lane layout regressed from strided 16B loads (2x TA transactions);
// confound removed here.

#define LEAKY(v) fmaxf((v), 0.2f * (v))

template <int CTRL>
__device__ __forceinline__ float dpp_add(float v) {
    int t = __builtin_amdgcn_update_dpp(0, __float_as_int(v), CTRL, 0xF, 0xF, true);
    return v + __int_as_float(t);
}

// sum over the 16 lanes of a subgroup (subgroups are 16-lane aligned)
__device__ __forceinline__ float red16(float v) {
    v = dpp_add<0xB1>(v);    // quad_perm [1,0,3,2] = lane^1
    v = dpp_add<0x4E>(v);    // quad_perm [2,3,0,1] = lane^2
    v = dpp_add<0x141>(v);   // row_half_mirror     = lane^4 (quads uniform)
    v = dpp_add<0x140>(v);   // row_mirror          = lane^8 (halves uniform)
    return v;
}

template <bool FIRST>
__global__ __launch_bounds__(256) void k_gat(const float* __restrict__ h,
                                             const int* __restrict__ cnt,
                                             const unsigned short* __restrict__ slots,
                                             const float* __restrict__ att_l,
                                             const float* __restrict__ bias_l,
                                             float* __restrict__ h_out,
                                             float* __restrict__ acc, int n) {
    int wid = threadIdx.x >> 6;
    int lane = threadIdx.x & 63;
    int node = blockIdx.x * 4 + wid;
    if (node >= n) return;
    int sub = lane >> 4, q = lane & 15;
    unsigned qb = (unsigned)q << 4;              // byte offset of quad in a row
    const char* hb = (const char*)h;
    float4 a0q = ((const float4*)att_l)[q];
    float4 a1q = ((const float4*)att_l)[16 + q];
    float4 hd = *(const float4*)(hb + (((unsigned)node << 8) + qb));
    int deg = cnt[node];
    if (deg > CAP) deg = CAP;
    const unsigned* rowu = (const unsigned*)(slots + (size_t)node * CAP);

    float s0, s1;
    float4 A0, A1;

    // self-loop: all 4 subgroups, weight 1/4 (merge sums restore 1x) — no branch
    {
        float vx = LEAKY(2.f * hd.x), vy = LEAKY(2.f * hd.y);
        float vz = LEAKY(2.f * hd.z), vw = LEAKY(2.f * hd.w);
        float p0 = vx * a0q.x + vy * a0q.y + vz * a0q.z + vw * a0q.w;
        float p1 = vx * a1q.x + vy * a1q.y + vz * a1q.z + vw * a1q.w;
        p0 = red16(p0);
        p1 = red16(p1);
        float e0 = 0.25f * __expf(p0), e1 = 0.25f * __expf(p1);
        s0 = e0; s1 = e1;
        A0.x = e0 * hd.x; A0.y = e0 * hd.y; A0.z = e0 * hd.z; A0.w = e0 * hd.w;
        A1.x = e1 * hd.x; A1.y = e1 * hd.y; A1.z = e1 * hd.z; A1.w = e1 * hd.w;
    }

    // main loop: subgroup takes edge pairs (2p, 2p+1) — one u32 = both indices
    int npair = deg >> 1;
    for (int p = sub; p < npair; p += 4) {
        unsigned pk = rowu[p];
        float4 va = *(const float4*)(hb + (((pk & 0xFFFFu) << 8) + qb));
        float4 vb = *(const float4*)(hb + (((pk >> 16) << 8) + qb));
        float vx, vy, vz, vw;
        vx = LEAKY(va.x + hd.x); vy = LEAKY(va.y + hd.y);
        vz = LEAKY(va.z + hd.z); vw = LEAKY(va.w + hd.w);
        float pa0 = vx * a0q.x + vy * a0q.y + vz * a0q.z + vw * a0q.w;
        float pa1 = vx * a1q.x + vy * a1q.y + vz * a1q.z + vw * a1q.w;
        vx = LEAKY(vb.x + hd.x); vy = LEAKY(vb.y + hd.y);
        vz = LEAKY(vb.z + hd.z); vw = LEAKY(vb.w + hd.w);
        float pb0 = vx * a0q.x + vy * a0q.y + vz * a0q.z + vw * a0q.w;
        float pb1 = vx * a1q.x + vy * a1q.y + vz * a1q.z + vw * a1q.w;
        pa0 = red16(pa0); pa1 = red16(pa1);
        pb0 = red16(pb0); pb1 = red16(pb1);
        float ea0 = __expf(pa0), ea1 = __expf(pa1);
        float eb0 = __expf(pb0), eb1 = __expf(pb1);
        s0 += ea0 + eb0;
        s1 += ea1 + eb1;
        A0.x += ea0 * va.x + eb0 * vb.x; A0.y += ea0 * va.y + eb0 * vb.y;
        A0.z += ea0 * va.z + eb0 * vb.z; A0.w += ea0 * va.w + eb0 * vb.w;
        A1.x += ea1 * va.x + eb1 * vb.x; A1.y += ea1 * va.y + eb1 * vb.y;
        A1.z += ea1 * va.z + eb1 * vb.z; A1.w += ea1 * va.w + eb1 * vb.w;
    }

    // tail: one odd edge, handled by one subgroup (uniform per subgroup)
    if (deg & 1) {
        int t = deg - 1;
        if (sub == ((t >> 1) & 3)) {
            unsigned s = ((const unsigned short*)rowu)[t];
            float4 hv = *(const float4*)(hb + ((s << 8) + qb));
            float vx = LEAKY(hv.x + hd.x), vy = LEAKY(hv.y + hd.y);
            float vz = LEAKY(hv.z + hd.z), vw = LEAKY(hv.w + hd.w);
            float p0 = vx * a0q.x + vy * a0q.y + vz * a0q.z + vw * a0q.w;
            float p1 = vx * a1q.x + vy * a1q.y + vz * a1q.z + vw * a1q.w;
            p0 = red16(p0);
            p1 = red16(p1);
            float e0 = __expf(p0), e1 = __expf(p1);
            s0 += e0; s1 += e1;
            A0.x += e0 * hv.x; A0.y += e0 * hv.y; A0.z += e0 * hv.z; A0.w += e0 * hv.w;
            A1.x += e1 * hv.x; A1.y += e1 * hv.y; A1.z += e1 * hv.z; A1.w += e1 * hv.w;
        }
    }

    // merge the 4 subgroups: plain sums (cross-row — DPP can't, keep shfl)
#pragma unroll
    for (int step = 16; step <= 32; step <<= 1) {
        s0 += __shfl_xor(s0, step);
        s1 += __shfl_xor(s1, step);
        A0.x += __shfl_xor(A0.x, step); A0.y += __shfl_xor(A0.y, step);
        A0.z += __shfl_xor(A0.z, step); A0.w += __shfl_xor(A0.w, step);
        A1.x += __shfl_xor(A1.x, step); A1.y += __shfl_xor(A1.y, step);
        A1.z += __shfl_xor(A1.z, step); A1.w += __shfl_xor(A1.w, step);
    }

    if (sub == 0) {
        float inv0 = 0.5f / (s0 + 1e-16f);       // fold mean-over-heads
        float inv1 = 0.5f / (s1 + 1e-16f);
        float4 b4 = ((const float4*)bias_l)[q];
        float4 o;
        o.x = A0.x * inv0 + A1.x * inv1 + b4.x;
        o.y = A0.y * inv0 + A1.y * inv1 + b4.y;
        o.z = A0.z * inv0 + A1.z * inv1 + b4.z;
        o.w = A0.w * inv0 + A1.w * inv1 + b4.w;
        ((float4*)h_out)[(size_t)node * 16 + q] = o;
        float4* accp = (float4*)acc + (size_t)node * 16 + q;
        float4 ac;
        if (FIRST) {
            // acc = 0.25*(x + h1); hd holds x's row quad
            ac.x = 0.25f * (hd.x + o.x); ac.y = 0.25f * (hd.y + o.y);
            ac.z = 0.25f * (hd.z + o.z); ac.w = 0.25f * (hd.w + o.w);
        } else {
            ac = *accp;
            ac.x += 0.25f * o.x; ac.y += 0.25f * o.y;
            ac.z += 0.25f * o.z; ac.w += 0.25f * o.w;
        }
        *accp = ac;
    }
}

// ---------------- launch ----------------

static inline size_t align256(size_t x) { return (x + 255) & ~(size_t)255; }

extern "C" void kernel_launch(void* const* d_in, const int* in_sizes, int n_in,
                              void* d_out, int out_size, void* d_ws, size_t ws_size,
                              hipStream_t stream) {
    const float* x    = (const float*)d_in[0];
    const int*   ei   = (const int*)d_in[1];
    const float* att  = (const float*)d_in[2];
    const float* bias = (const float*)d_in[3];
    float* acc = (float*)d_out;   // fp32 output; feats-mean accumulated here

    char* w = (char*)d_ws;
    int* bcnt   = (int*)w;              w += align256((size_t)NB * sizeof(int));
    int* cnt    = (int*)w;              w += align256((size_t)NN * sizeof(int));
    unsigned int* bucket = (unsigned int*)w;
    w += align256((size_t)NB * BCAP * sizeof(unsigned int));
    unsigned short* slots = (unsigned short*)w;
    w += align256((size_t)NN * CAP * sizeof(unsigned short));
    float* hA   = (float*)w;            w += align256((size_t)NN * CC * sizeof(float));
    float* hB   = (float*)w;            w += align256((size_t)NN * CC * sizeof(float));

    const int B = 256;

    // build (per call; ws is re-poisoned before every launch)
    hipMemsetAsync(bcnt, 0, (size_t)NB * sizeof(int), stream);
    k_bin<<<NBLK, 1024, 0, stream>>>(ei, bcnt, bucket);
    k_place<<<NB, B, 0, stream>>>(bucket, bcnt, cnt, slots);

    // 3 fused GAT layers; layer 0 reads x directly and seeds acc = 0.25*(x + h1)
    k_gat<true><<<(NN + 3) / 4, B, 0, stream>>>(
        x, cnt, slots, att, bias, hA, acc, NN);
    k_gat<false><<<(NN + 3) / 4, B, 0, stream>>>(
        hA, cnt, slots, att + (size_t)HH * CC, bias + CC, hB, acc, NN);
    k_gat<false><<<(NN + 3) / 4, B, 0, stream>>>(
        hB, cnt, slots, att + (size_t)2 * HH * CC, bias + 2 * CC, hA, acc, NN);
}